// Round 16
// baseline (80.212 us; speedup 1.0000x reference)
//
#include <hip/hip_runtime.h>
#include <math.h>

#define DD 256
#define SS 64
#define BT 2048

typedef __attribute__((ext_vector_type(4))) float f32x4;
typedef __attribute__((ext_vector_type(8))) short bf16x8;
typedef __attribute__((ext_vector_type(4))) unsigned int u32x4;

typedef __attribute__((address_space(3))) unsigned lds_u32;
typedef const __attribute__((address_space(1))) unsigned glb_u32;

__device__ inline unsigned pack_bf16(float a, float b) {
    unsigned ua = __builtin_bit_cast(unsigned, a);
    unsigned ub = __builtin_bit_cast(unsigned, b);
    ua = (ua + 0x7fffu + ((ua >> 16) & 1u)) >> 16;
    ub = (ub + 0x7fffu + ((ub >> 16) & 1u)) >> 16;
    return ua | (ub << 16);
}

// K1: BN + FC1(relu) + FC2 -> transHs. grid=(64) block=(1024).
__global__ __launch_bounds__(1024) void
k_trans(const float* __restrict__ Hs, const float* __restrict__ g,
        const float* __restrict__ b, const float* __restrict__ s_w1,
        const float* __restrict__ s_b1, const float* __restrict__ s_w2,
        const float* __restrict__ s_b2, float* __restrict__ transHs) {
    __shared__ float rowA[DD], rowB[DD];
    __shared__ float red[8][DD];
    const int s = blockIdx.x;
    const int j = threadIdx.x & 255, kw = threadIdx.x >> 8;
    float sum = 0.f, sumsq = 0.f;
#pragma unroll
    for (int s2 = kw * 16; s2 < kw * 16 + 16; ++s2) {
        float v = Hs[s2 * DD + j];
        sum += v; sumsq += v * v;
    }
    red[kw][j] = sum; red[4 + kw][j] = sumsq;
    __syncthreads();
    if (kw == 0) {
        float st = red[0][j] + red[1][j] + red[2][j] + red[3][j];
        float sq = red[4][j] + red[5][j] + red[6][j] + red[7][j];
        float mu  = st * (1.f / SS);
        float var = sq * (1.f / SS) - mu * mu;
        rowA[j] = (Hs[s * DD + j] - mu) * rsqrtf(var + 1e-5f) * g[j] + b[j];
    }
    __syncthreads();
    float a1 = 0.f;
#pragma unroll 16
    for (int d = kw * 64; d < kw * 64 + 64; ++d)
        a1 = fmaf(rowA[d], s_w1[d * DD + j], a1);
    red[kw][j] = a1;
    __syncthreads();
    if (kw == 0)
        rowB[j] = fmaxf(red[0][j] + red[1][j] + red[2][j] + red[3][j] + s_b1[j], 0.f);
    __syncthreads();
    float a2 = 0.f;
#pragma unroll 16
    for (int d = kw * 64; d < kw * 64 + 64; ++d)
        a2 = fmaf(rowB[d], s_w2[d * DD + j], a2);
    red[kw][j] = a2;
    __syncthreads();
    if (kw == 0)
        transHs[s * DD + j] = red[0][j] + red[1][j] + red[2][j] + red[3][j] + s_b2[j];
}

// K2: everything that depends only on transHs (or nothing). grid=(160) block=(1024).
//  [0,64):    S1b[s] = transHs[s] @ w_w1[256:512] + w_b1   (GEMV, 4-way K split)
//  [64,128):  Apack = bf16(Hx) in A-fragment order
//  [128,160): Bs = bf16(W1a + m_s*C) in B-fragment order (16 slots per thread-frag)
__global__ __launch_bounds__(1024) void
k_stage(const float* __restrict__ w_w1, const float* __restrict__ w_b1,
        const float* __restrict__ Hx, const float* __restrict__ transHs,
        float* __restrict__ S1b, unsigned* __restrict__ Apack,
        unsigned* __restrict__ Bs) {
    const int bid = blockIdx.x;
    const int tid = threadIdx.x;
    if (bid < 64) {
        __shared__ float rowC[DD];
        __shared__ float red[4][DD];
        const int s = bid;
        const int j = tid & 255, kw = tid >> 8;
        if (kw == 0) rowC[j] = transHs[s * DD + j];
        __syncthreads();
        float a3 = 0.f;
#pragma unroll 16
        for (int d = kw * 64; d < kw * 64 + 64; ++d)
            a3 = fmaf(rowC[d], w_w1[(256 + d) * DD + j], a3);
        red[kw][j] = a3;
        __syncthreads();
        if (kw == 0)
            S1b[s * DD + j] = red[0][j] + red[1][j] + red[2][j] + red[3][j] + w_b1[j];
    } else if (bid < 128) {
        int idx = (bid - 64) * 1024 + tid;          // 0..65535
        int lane = idx & 63, ks = (idx >> 6) & 7, MT = idx >> 9;
        int t  = MT * 16 + (lane & 15);
        int k0 = ks * 32 + (lane >> 4) * 8;
        const float* src = Hx + t * DD + k0;
        float4 x0 = *(const float4*)src;
        float4 x1 = *(const float4*)(src + 4);
        unsigned p[4];
        p[0] = pack_bf16(x0.x, x0.y);
        p[1] = pack_bf16(x0.z, x0.w);
        p[2] = pack_bf16(x1.x, x1.y);
        p[3] = pack_bf16(x1.z, x1.w);
        *(u32x4*)(Apack + idx * 4) = *(const u32x4*)p;
    } else {
        __shared__ float ms_l[16][DD];
        const int b2 = bid - 128;                   // 0..31
        const int ic = b2 & 7, sg = b2 >> 3;        // 8 idx-chunks x 4 slot-groups
        const int s0 = sg * 16;
#pragma unroll
        for (int i = 0; i < 4; ++i) {
            int e4 = i * 1024 + tid;
            if (e4 < 1024) ((float4*)ms_l)[e4] = ((const float4*)(transHs + s0 * DD))[e4];
        }
        __syncthreads();
        const int idx = ic * 1024 + tid;            // 0..8191
        const int lane = idx & 63, ks = (idx >> 6) & 7, nt = idx >> 9;
        const int j  = nt * 16 + (lane & 15);
        const int k0 = ks * 32 + (lane >> 4) * 8;
        const float* C = w_w1 + 512 * DD;
        float w1v[8], cv[8];
#pragma unroll
        for (int e = 0; e < 8; ++e) {
            w1v[e] = w_w1[(k0 + e) * DD + j];
            cv[e]  = C[(k0 + e) * DD + j];
        }
        for (int ss = 0; ss < 16; ++ss) {
            unsigned p[4];
#pragma unroll
            for (int e = 0; e < 4; ++e) {
                float f0 = w1v[2 * e]     + ms_l[ss][k0 + 2 * e]     * cv[2 * e];
                float f1 = w1v[2 * e + 1] + ms_l[ss][k0 + 2 * e + 1] * cv[2 * e + 1];
                p[e] = pack_bf16(f0, f1);
            }
            *(u32x4*)(Bs + ((s0 + ss) * 8192 + idx) * 4) = *(const u32x4*)p;
        }
    }
}

// atten[t][s] = w2 . relu( A@Bs[s] + S1b[s] ) + b2
// grid=(1024) XCD-decoded; block=256 (4 waves); ks-loop double-buffered;
// B (L2, long latency) prefetched before A (LDS); setprio around MFMA cluster.
__global__ __launch_bounds__(256, 2) void
k_main_mfma(const unsigned* __restrict__ Apack, const unsigned* __restrict__ Bs,
            const float* __restrict__ S1b, const float* __restrict__ w2,
            const float* __restrict__ w_b2, float* __restrict__ atten) {
    __shared__ unsigned Albs[16384];            // 64 KB; reused as reduce scratch
    const int swz  = (blockIdx.x & 7) * 128 + (blockIdx.x >> 3);
    const int s    = swz >> 4;                  // slot
    const int tile = swz & 15;                  // token tile (128 tokens)
    const int t0 = tile * 128;
    const int tid = threadIdx.x;
    const int w = tid >> 6, l = tid & 63;
    const int lrow = l & 15, lg = l >> 4;
    const unsigned* Asrc = Apack + tile * 16384;
    const unsigned* Bsl  = Bs + s * 32768;

#pragma unroll
    for (int i = 0; i < 16; ++i) {
        int chunk = w * 16 + i;
        __builtin_amdgcn_global_load_lds((glb_u32*)(Asrc + chunk * 256 + l * 4),
                                         (lds_u32*)(Albs + chunk * 256), 16, 0, 0);
    }
    __syncthreads();

    f32x4 acc[8][4] = {};
    bf16x8 af[2][8];
    bf16x8 bf[2][4];

#pragma unroll
    for (int nt = 0; nt < 4; ++nt)
        bf[0][nt] = *(const bf16x8*)(Bsl + (((w * 4 + nt) * 8 + 0) * 64 + l) * 4);
#pragma unroll
    for (int mt = 0; mt < 8; ++mt)
        af[0][mt] = *(const bf16x8*)((const char*)Albs + ((mt * 8 + 0) * 64 + l) * 16);

#pragma unroll
    for (int ks = 0; ks < 8; ++ks) {
        const int cur = ks & 1, nxt = cur ^ 1;
        if (ks < 7) {
            // longer-latency B (L2) first, then A (LDS)
#pragma unroll
            for (int nt = 0; nt < 4; ++nt)
                bf[nxt][nt] = *(const bf16x8*)(Bsl + (((w * 4 + nt) * 8 + ks + 1) * 64 + l) * 4);
#pragma unroll
            for (int mt = 0; mt < 8; ++mt)
                af[nxt][mt] = *(const bf16x8*)((const char*)Albs + ((mt * 8 + ks + 1) * 64 + l) * 16);
        }
        __builtin_amdgcn_s_setprio(1);
#pragma unroll
        for (int nt = 0; nt < 4; ++nt)
#pragma unroll
            for (int mt = 0; mt < 8; ++mt)
                acc[mt][nt] = __builtin_amdgcn_mfma_f32_16x16x32_bf16(af[cur][mt], bf[cur][nt], acc[mt][nt], 0, 0, 0);
        __builtin_amdgcn_s_setprio(0);
    }
    __syncthreads();                            // A reads done before LDS reuse

    float* attp = (float*)Albs;                 // [4][128]
    float s1[4], w2v[4];
#pragma unroll
    for (int nt = 0; nt < 4; ++nt) {
        int jn = (w * 4 + nt) * 16 + lrow;
        s1[nt]  = S1b[s * DD + jn];
        w2v[nt] = w2[jn];
    }
#pragma unroll
    for (int mt = 0; mt < 8; ++mt) {
#pragma unroll
        for (int i = 0; i < 4; ++i) {
            float p = 0.f;
#pragma unroll
            for (int nt = 0; nt < 4; ++nt) {
                float h = fmaxf(acc[mt][nt][i] + s1[nt], 0.f);
                p = fmaf(h, w2v[nt], p);
            }
            p += __shfl_xor(p, 1);
            p += __shfl_xor(p, 2);
            p += __shfl_xor(p, 4);
            p += __shfl_xor(p, 8);
            if (lrow == 0) attp[w * 128 + mt * 16 + lg * 4 + i] = p;
        }
    }
    __syncthreads();
    if (tid < 128) {
        float r = attp[tid] + attp[128 + tid] + attp[256 + tid] + attp[384 + tid] + w_b2[0];
        atten[(t0 + tid) * SS + s] = r;
    }
}

// softmax over slots + G = score@transHs + output. grid=(128) block=(256):
// transHs staged ONCE per block in LDS (64 KB), 16 tokens/block (4 per wave).
__global__ __launch_bounds__(256) void
k_out(const float* __restrict__ Hx, const float* __restrict__ m,
      const float* __restrict__ atten, float* __restrict__ outU,
      float* __restrict__ outA) {
    __shared__ float th[SS][DD];                // 64 KB
    const int tid = threadIdx.x;
    const int wave = tid >> 6, lane = tid & 63;
#pragma unroll
    for (int i = 0; i < 16; ++i)
        ((float4*)th)[i * 256 + tid] = ((const float4*)m)[i * 256 + tid];
    __syncthreads();
    const int tb = blockIdx.x * 16 + wave * 4;
#pragma unroll
    for (int tt = 0; tt < 4; ++tt) {
        const int t = tb + tt;
        float a = atten[t * SS + lane];
        float mx = a;
#pragma unroll
        for (int off = 32; off; off >>= 1) mx = fmaxf(mx, __shfl_xor(mx, off));
        float e = __expf(a - mx);
        float sum = e;
#pragma unroll
        for (int off = 32; off; off >>= 1) sum += __shfl_xor(sum, off);
        float p = e / sum;
        outA[t * SS + lane] = p;
        float gacc[4] = {};
        for (int s = 0; s < SS; ++s) {
            float ps = __shfl(p, s);
#pragma unroll
            for (int q = 0; q < 4; ++q)
                gacc[q] = fmaf(ps, th[s][lane + 64 * q], gacc[q]);
        }
#pragma unroll
        for (int q = 0; q < 4; ++q) {
            int j = lane + 64 * q;
            float x = Hx[t * DD + j];
            outU[t * 2 * DD + j] = x;
            outU[t * 2 * DD + DD + j] = x + gacc[q];
        }
    }
}

extern "C" void kernel_launch(void* const* d_in, const int* in_sizes, int n_in,
                              void* d_out, int out_size, void* d_ws, size_t ws_size,
                              hipStream_t stream) {
    const float* Hx   = (const float*)d_in[0];
    const float* Hs   = (const float*)d_in[1];
    const float* bn_g = (const float*)d_in[2];
    const float* bn_b = (const float*)d_in[3];
    const float* s_w1 = (const float*)d_in[4];
    const float* s_b1 = (const float*)d_in[5];
    const float* s_w2 = (const float*)d_in[6];
    const float* s_b2 = (const float*)d_in[7];
    const float* w_w1 = (const float*)d_in[8];
    const float* w_b1 = (const float*)d_in[9];
    const float* w_w2 = (const float*)d_in[10];
    const float* w_b2 = (const float*)d_in[11];

    float* ws      = (float*)d_ws;
    float* transHs = ws;                        // 16384 f
    float* S1b     = ws + 16384;                // 16384 f
    float* atten   = ws + 32768;                // 131072 f
    unsigned* Apack = (unsigned*)(ws + 163840); // 262144 u32 (1 MB)
    unsigned* Bs    = Apack + 262144;           // 2097152 u32 (8 MB)

    float* outU = (float*)d_out;                // [2048][512]
    float* outA = outU + BT * 2 * DD;           // [2048][64]

    k_trans<<<SS, 1024, 0, stream>>>(Hs, bn_g, bn_b, s_w1, s_b1, s_w2, s_b2, transHs);
    k_stage<<<160, 1024, 0, stream>>>(w_w1, w_b1, Hx, transHs, S1b, Apack, Bs);
    k_main_mfma<<<1024, 256, 0, stream>>>(Apack, Bs, S1b, w_w2, w_b2, atten);
    k_out<<<BT / 16, 256, 0, stream>>>(Hx, transHs, atten, outU, outA);
}

// Round 17
// 54.481 us; speedup vs baseline: 1.4723x; 1.4723x over previous
//
#include <hip/hip_runtime.h>
#include <math.h>

#define DD 256
#define SS 64
#define BT 2048

typedef __attribute__((ext_vector_type(4))) float f32x4;
typedef __attribute__((ext_vector_type(8))) short bf16x8;
typedef __attribute__((ext_vector_type(4))) unsigned int u32x4;

typedef __attribute__((address_space(3))) unsigned lds_u32;
typedef const __attribute__((address_space(1))) unsigned glb_u32;

__device__ inline unsigned pack_bf16(float a, float b) {
    unsigned ua = __builtin_bit_cast(unsigned, a);
    unsigned ub = __builtin_bit_cast(unsigned, b);
    ua = (ua + 0x7fffu + ((ua >> 16) & 1u)) >> 16;
    ub = (ub + 0x7fffu + ((ub >> 16) & 1u)) >> 16;
    return ua | (ub << 16);
}

// K1: BN + FC1(relu) + FC2 -> transHs. grid=(64) block=(1024).
__global__ __launch_bounds__(1024) void
k_trans(const float* __restrict__ Hs, const float* __restrict__ g,
        const float* __restrict__ b, const float* __restrict__ s_w1,
        const float* __restrict__ s_b1, const float* __restrict__ s_w2,
        const float* __restrict__ s_b2, float* __restrict__ transHs) {
    __shared__ float rowA[DD], rowB[DD];
    __shared__ float red[8][DD];
    const int s = blockIdx.x;
    const int j = threadIdx.x & 255, kw = threadIdx.x >> 8;
    float sum = 0.f, sumsq = 0.f;
#pragma unroll
    for (int s2 = kw * 16; s2 < kw * 16 + 16; ++s2) {
        float v = Hs[s2 * DD + j];
        sum += v; sumsq += v * v;
    }
    red[kw][j] = sum; red[4 + kw][j] = sumsq;
    __syncthreads();
    if (kw == 0) {
        float st = red[0][j] + red[1][j] + red[2][j] + red[3][j];
        float sq = red[4][j] + red[5][j] + red[6][j] + red[7][j];
        float mu  = st * (1.f / SS);
        float var = sq * (1.f / SS) - mu * mu;
        rowA[j] = (Hs[s * DD + j] - mu) * rsqrtf(var + 1e-5f) * g[j] + b[j];
    }
    __syncthreads();
    float a1 = 0.f;
#pragma unroll 16
    for (int d = kw * 64; d < kw * 64 + 64; ++d)
        a1 = fmaf(rowA[d], s_w1[d * DD + j], a1);
    red[kw][j] = a1;
    __syncthreads();
    if (kw == 0)
        rowB[j] = fmaxf(red[0][j] + red[1][j] + red[2][j] + red[3][j] + s_b1[j], 0.f);
    __syncthreads();
    float a2 = 0.f;
#pragma unroll 16
    for (int d = kw * 64; d < kw * 64 + 64; ++d)
        a2 = fmaf(rowB[d], s_w2[d * DD + j], a2);
    red[kw][j] = a2;
    __syncthreads();
    if (kw == 0)
        transHs[s * DD + j] = red[0][j] + red[1][j] + red[2][j] + red[3][j] + s_b2[j];
}

// K2: everything that depends only on transHs (or nothing). grid=(160) block=(1024).
//  [0,64):    S1b[s] = transHs[s] @ w_w1[256:512] + w_b1   (GEMV, 4-way K split)
//  [64,128):  Apack = bf16(Hx) in A-fragment order
//  [128,160): Bs = bf16(W1a + m_s*C) in B-fragment order (16 slots per thread-frag)
__global__ __launch_bounds__(1024) void
k_stage(const float* __restrict__ w_w1, const float* __restrict__ w_b1,
        const float* __restrict__ Hx, const float* __restrict__ transHs,
        float* __restrict__ S1b, unsigned* __restrict__ Apack,
        unsigned* __restrict__ Bs) {
    const int bid = blockIdx.x;
    const int tid = threadIdx.x;
    if (bid < 64) {
        __shared__ float rowC[DD];
        __shared__ float red[4][DD];
        const int s = bid;
        const int j = tid & 255, kw = tid >> 8;
        if (kw == 0) rowC[j] = transHs[s * DD + j];
        __syncthreads();
        float a3 = 0.f;
#pragma unroll 16
        for (int d = kw * 64; d < kw * 64 + 64; ++d)
            a3 = fmaf(rowC[d], w_w1[(256 + d) * DD + j], a3);
        red[kw][j] = a3;
        __syncthreads();
        if (kw == 0)
            S1b[s * DD + j] = red[0][j] + red[1][j] + red[2][j] + red[3][j] + w_b1[j];
    } else if (bid < 128) {
        int idx = (bid - 64) * 1024 + tid;          // 0..65535
        int lane = idx & 63, ks = (idx >> 6) & 7, MT = idx >> 9;
        int t  = MT * 16 + (lane & 15);
        int k0 = ks * 32 + (lane >> 4) * 8;
        const float* src = Hx + t * DD + k0;
        float4 x0 = *(const float4*)src;
        float4 x1 = *(const float4*)(src + 4);
        unsigned p[4];
        p[0] = pack_bf16(x0.x, x0.y);
        p[1] = pack_bf16(x0.z, x0.w);
        p[2] = pack_bf16(x1.x, x1.y);
        p[3] = pack_bf16(x1.z, x1.w);
        *(u32x4*)(Apack + idx * 4) = *(const u32x4*)p;
    } else {
        __shared__ float ms_l[16][DD];
        const int b2 = bid - 128;                   // 0..31
        const int ic = b2 & 7, sg = b2 >> 3;        // 8 idx-chunks x 4 slot-groups
        const int s0 = sg * 16;
#pragma unroll
        for (int i = 0; i < 4; ++i) {
            int e4 = i * 1024 + tid;
            if (e4 < 1024) ((float4*)ms_l)[e4] = ((const float4*)(transHs + s0 * DD))[e4];
        }
        __syncthreads();
        const int idx = ic * 1024 + tid;            // 0..8191
        const int lane = idx & 63, ks = (idx >> 6) & 7, nt = idx >> 9;
        const int j  = nt * 16 + (lane & 15);
        const int k0 = ks * 32 + (lane >> 4) * 8;
        const float* C = w_w1 + 512 * DD;
        float w1v[8], cv[8];
#pragma unroll
        for (int e = 0; e < 8; ++e) {
            w1v[e] = w_w1[(k0 + e) * DD + j];
            cv[e]  = C[(k0 + e) * DD + j];
        }
        for (int ss = 0; ss < 16; ++ss) {
            unsigned p[4];
#pragma unroll
            for (int e = 0; e < 4; ++e) {
                float f0 = w1v[2 * e]     + ms_l[ss][k0 + 2 * e]     * cv[2 * e];
                float f1 = w1v[2 * e + 1] + ms_l[ss][k0 + 2 * e + 1] * cv[2 * e + 1];
                p[e] = pack_bf16(f0, f1);
            }
            *(u32x4*)(Bs + ((s0 + ss) * 8192 + idx) * 4) = *(const u32x4*)p;
        }
    }
}

// atten[t][s] = w2 . relu( A@Bs[s] + S1b[s] ) + b2
// grid=(1024) XCD-decoded; block=256 (4 waves); ks-loop double-buffered;
// s_setprio(1) around the MFMA cluster (T5: waves are barrier-free in the loop).
__global__ __launch_bounds__(256, 2) void
k_main_mfma(const unsigned* __restrict__ Apack, const unsigned* __restrict__ Bs,
            const float* __restrict__ S1b, const float* __restrict__ w2,
            const float* __restrict__ w_b2, float* __restrict__ atten) {
    __shared__ unsigned Albs[16384];            // 64 KB; reused as reduce scratch
    const int swz  = (blockIdx.x & 7) * 128 + (blockIdx.x >> 3);
    const int s    = swz >> 4;                  // slot
    const int tile = swz & 15;                  // token tile (128 tokens)
    const int t0 = tile * 128;
    const int tid = threadIdx.x;
    const int w = tid >> 6, l = tid & 63;
    const int lrow = l & 15, lg = l >> 4;
    const unsigned* Asrc = Apack + tile * 16384;
    const unsigned* Bsl  = Bs + s * 32768;

#pragma unroll
    for (int i = 0; i < 16; ++i) {
        int chunk = w * 16 + i;
        __builtin_amdgcn_global_load_lds((glb_u32*)(Asrc + chunk * 256 + l * 4),
                                         (lds_u32*)(Albs + chunk * 256), 16, 0, 0);
    }
    __syncthreads();

    f32x4 acc[8][4] = {};
    bf16x8 af[2][8];
    bf16x8 bf[2][4];

#pragma unroll
    for (int mt = 0; mt < 8; ++mt)
        af[0][mt] = *(const bf16x8*)((const char*)Albs + ((mt * 8 + 0) * 64 + l) * 16);
#pragma unroll
    for (int nt = 0; nt < 4; ++nt)
        bf[0][nt] = *(const bf16x8*)(Bsl + (((w * 4 + nt) * 8 + 0) * 64 + l) * 4);

#pragma unroll
    for (int ks = 0; ks < 8; ++ks) {
        const int cur = ks & 1, nxt = cur ^ 1;
        if (ks < 7) {
#pragma unroll
            for (int mt = 0; mt < 8; ++mt)
                af[nxt][mt] = *(const bf16x8*)((const char*)Albs + ((mt * 8 + ks + 1) * 64 + l) * 16);
#pragma unroll
            for (int nt = 0; nt < 4; ++nt)
                bf[nxt][nt] = *(const bf16x8*)(Bsl + (((w * 4 + nt) * 8 + ks + 1) * 64 + l) * 4);
        }
        __builtin_amdgcn_s_setprio(1);
#pragma unroll
        for (int nt = 0; nt < 4; ++nt)
#pragma unroll
            for (int mt = 0; mt < 8; ++mt)
                acc[mt][nt] = __builtin_amdgcn_mfma_f32_16x16x32_bf16(af[cur][mt], bf[cur][nt], acc[mt][nt], 0, 0, 0);
        __builtin_amdgcn_s_setprio(0);
    }
    __syncthreads();                            // A reads done before LDS reuse

    float* attp = (float*)Albs;                 // [4][128]
    float s1[4], w2v[4];
#pragma unroll
    for (int nt = 0; nt < 4; ++nt) {
        int jn = (w * 4 + nt) * 16 + lrow;
        s1[nt]  = S1b[s * DD + jn];
        w2v[nt] = w2[jn];
    }
#pragma unroll
    for (int mt = 0; mt < 8; ++mt) {
#pragma unroll
        for (int i = 0; i < 4; ++i) {
            float p = 0.f;
#pragma unroll
            for (int nt = 0; nt < 4; ++nt) {
                float h = fmaxf(acc[mt][nt][i] + s1[nt], 0.f);
                p = fmaf(h, w2v[nt], p);
            }
            p += __shfl_xor(p, 1);
            p += __shfl_xor(p, 2);
            p += __shfl_xor(p, 4);
            p += __shfl_xor(p, 8);
            if (lrow == 0) attp[w * 128 + mt * 16 + lg * 4 + i] = p;
        }
    }
    __syncthreads();
    if (tid < 128) {
        float r = attp[tid] + attp[128 + tid] + attp[256 + tid] + attp[384 + tid] + w_b2[0];
        atten[(t0 + tid) * SS + s] = r;
    }
}

// softmax over slots + G = score@transHs + output assembly. grid=(512) block=(256)
__global__ __launch_bounds__(256) void
k_out(const float* __restrict__ Hx, const float* __restrict__ m,
      const float* __restrict__ atten, float* __restrict__ outU,
      float* __restrict__ outA) {
    int wave = threadIdx.x >> 6, lane = threadIdx.x & 63;
    int t = blockIdx.x * 4 + wave;
    float a = atten[t * SS + lane];
    float mx = a;
#pragma unroll
    for (int off = 32; off; off >>= 1) mx = fmaxf(mx, __shfl_xor(mx, off));
    float e = __expf(a - mx);
    float sum = e;
#pragma unroll
    for (int off = 32; off; off >>= 1) sum += __shfl_xor(sum, off);
    float p = e / sum;
    outA[t * SS + lane] = p;
    float gacc[4] = {};
    for (int s = 0; s < SS; ++s) {
        float ps = __shfl(p, s);
#pragma unroll
        for (int q = 0; q < 4; ++q)
            gacc[q] = fmaf(ps, m[s * DD + lane + 64 * q], gacc[q]);
    }
#pragma unroll
    for (int q = 0; q < 4; ++q) {
        int j = lane + 64 * q;
        float x = Hx[t * DD + j];
        outU[t * 2 * DD + j] = x;
        outU[t * 2 * DD + DD + j] = x + gacc[q];
    }
}

extern "C" void kernel_launch(void* const* d_in, const int* in_sizes, int n_in,
                              void* d_out, int out_size, void* d_ws, size_t ws_size,
                              hipStream_t stream) {
    const float* Hx   = (const float*)d_in[0];
    const float* Hs   = (const float*)d_in[1];
    const float* bn_g = (const float*)d_in[2];
    const float* bn_b = (const float*)d_in[3];
    const float* s_w1 = (const float*)d_in[4];
    const float* s_b1 = (const float*)d_in[5];
    const float* s_w2 = (const float*)d_in[6];
    const float* s_b2 = (const float*)d_in[7];
    const float* w_w1 = (const float*)d_in[8];
    const float* w_b1 = (const float*)d_in[9];
    const float* w_w2 = (const float*)d_in[10];
    const float* w_b2 = (const float*)d_in[11];

    float* ws      = (float*)d_ws;
    float* transHs = ws;                        // 16384 f
    float* S1b     = ws + 16384;                // 16384 f
    float* atten   = ws + 32768;                // 131072 f
    unsigned* Apack = (unsigned*)(ws + 163840); // 262144 u32 (1 MB)
    unsigned* Bs    = Apack + 262144;           // 2097152 u32 (8 MB)

    float* outU = (float*)d_out;                // [2048][512]
    float* outA = outU + BT * 2 * DD;           // [2048][64]

    k_trans<<<SS, 1024, 0, stream>>>(Hs, bn_g, bn_b, s_w1, s_b1, s_w2, s_b2, transHs);
    k_stage<<<160, 1024, 0, stream>>>(w_w1, w_b1, Hx, transHs, S1b, Apack, Bs);
    k_main_mfma<<<1024, 256, 0, stream>>>(Apack, Bs, S1b, w_w2, w_b2, atten);
    k_out<<<BT / 4, 256, 0, stream>>>(Hx, transHs, atten, outU, outA);
}